// Round 24
// baseline (193.563 us; speedup 1.0000x reference)
//
#include <hip/hip_runtime.h>
#include <hip/hip_cooperative_groups.h>

namespace cg = cooperative_groups;

typedef float f32x4 __attribute__((ext_vector_type(4)));
typedef float f32x16 __attribute__((ext_vector_type(16)));
typedef short bf16x8 __attribute__((ext_vector_type(8)));

#define HW_ 1024
#define NE_ 4096
#define CHW_ 65536          // 64*1024
#define ZQ_SIZE 1048576
#define LOSS_OFF ZQ_SIZE
#define IDX_OFF (ZQ_SIZE + 1)
#define LOSS_SCALE (1.25f / 1048576.f)
#define EPS_GAP 0.1f        // 0.5*d2 scale; covers 12-bit trunc (~0.016) + split err (~1e-5)

union FragU { unsigned u[4]; bf16x8 v; };

__device__ __forceinline__ unsigned umin_(unsigned a, unsigned b) { return a < b ? a : b; }
__device__ __forceinline__ unsigned umax_(unsigned a, unsigned b) { return a > b ? a : b; }

// running top-2 update: s2 = median(key, s1, s2) ; s1 = min(s1, key)
// NOT idempotent under duplicate streams (R19 lesson).
__device__ __forceinline__ void top2_(unsigned key, unsigned& s1, unsigned& s2) {
    unsigned t;
    asm("v_med3_u32 %0, %1, %2, %3" : "=v"(t) : "v"(key), "v"(s1), "v"(s2));
    s2 = t;
    s1 = umin_(s1, key);
}

// split 8 f32 -> hi/lo bf16 fragments (truncation split; lo captures the tail)
__device__ __forceinline__ void split8(const float* v, FragU& hi, FragU& lo) {
#pragma unroll
    for (int p = 0; p < 4; p++) {
        float a = v[2 * p], b = v[2 * p + 1];
        unsigned ua = __float_as_uint(a), ub = __float_as_uint(b);
        hi.u[p] = (ua >> 16) | (ub & 0xFFFF0000u);
        float la = a - __uint_as_float(ua & 0xFFFF0000u);
        float lb = b - __uint_as_float(ub & 0xFFFF0000u);
        lo.u[p] = (__float_as_uint(la) >> 16) | (__float_as_uint(lb) & 0xFFFF0000u);
    }
}

__device__ __forceinline__ void gload_lds16(const void* g, void* l) {
    __builtin_amdgcn_global_load_lds(
        (const __attribute__((address_space(1))) unsigned*)g,
        (__attribute__((address_space(3))) unsigned*)l, 16, 0, 0);
}

// ---- single cooperative kernel: eprep | scan | final ---------------------
// Grid 256 x 512 (1 block/CU, co-resident). Phase A builds efrag32
// ([tile(128)][hi,lo][ks(4)][lane] x16B, negated, split) + h_e + loss=0.
// Phase B = R23's 32x32x16 MFMA scan (es=bid>>5, rb=bid&31 XCD mapping).
// Phase C = R23's vq_final on tid<256 (merge 8 partials, fp64 duel, outputs).
__global__ __launch_bounds__(512) void vq_all(
        const float* __restrict__ z, const float* __restrict__ emb,
        char* __restrict__ efrag, float* __restrict__ h_e,
        unsigned* __restrict__ k1q, unsigned* __restrict__ k2q,
        float* __restrict__ out) {
    __shared__ char buf[2][32768];
    __shared__ __attribute__((aligned(16))) float sh_he[512];

    cg::grid_group grid = cg::this_grid();

    const int tid = threadIdx.x;
    const int lane = tid & 63;
    const int w = tid >> 6;

    // ================= phase A: eprep =====================================
    {
        int gid = blockIdx.x * 512 + tid;     // 131072 threads
        if (gid < 32768) {                    // efrag32 build (negate+split)
            int l = gid & 63, ks = (gid >> 6) & 3, t = gid >> 8;   // t 0..127
            int erow = t * 32 + (l & 31);
            int k0 = ks * 16 + (l >> 5) * 8;
            const float* ep = emb + (size_t)erow * 64 + k0;
            float4 ea = *(const float4*)(ep);
            float4 eb = *(const float4*)(ep + 4);
            float v[8];
            v[0] = -ea.x; v[1] = -ea.y; v[2] = -ea.z; v[3] = -ea.w;
            v[4] = -eb.x; v[5] = -eb.y; v[6] = -eb.z; v[7] = -eb.w;
            FragU hi, lo;
            split8(v, hi, lo);
            char* base = efrag + (size_t)t * 8192 + ks * 1024 + l * 16;
            *(FragU*)(base)        = hi;
            *(FragU*)(base + 4096) = lo;
        } else if (gid < 36864) {             // h_e
            int t = gid - 32768;              // 0..4095
            const float4* er = (const float4*)(emb + (size_t)t * 64);
            float s = 0.f;
#pragma unroll
            for (int k = 0; k < 16; k++) {
                float4 e4 = er[k];
                s = fmaf(e4.x, e4.x, s); s = fmaf(e4.y, e4.y, s);
                s = fmaf(e4.z, e4.z, s); s = fmaf(e4.w, e4.w, s);
            }
            h_e[t] = 0.5f * s;
        } else if (gid == 36864) {
            out[LOSS_OFF] = 0.f;
        }
    }
    __threadfence();
    grid.sync();

    // ================= phase B: 32x32x16 MFMA scan ========================
    const int col = lane & 31;
    const int kgrp = lane >> 5;       // k-octet group (0..1)
    const int es = blockIdx.x >> 5;   // e-split (512 e = 16 tiles32)
    const int rb = blockIdx.x & 31;   // row-group (512 rows); bid%8 == rb%8
    const int e0t = es * 16;          // first tile32 of split
    const int b = rb >> 1;            // batch image (block never crosses)
    const int row0 = rb * 512 + w * 64;   // wave's 64 rows (2 z-tiles)

    sh_he[tid] = h_e[es * 512 + tid];

    // stage chunk 0: wave w stages tile (w>>1), part (w&1)
    {
        const char* src = efrag + (size_t)(e0t + (w >> 1)) * 8192
                          + (w & 1) * 4096 + lane * 16;
        char* dst = buf[0] + (w >> 1) * 8192 + (w & 1) * 4096;
#pragma unroll
        for (int i = 0; i < 4; i++) gload_lds16(src + i * 1024, dst + i * 1024);
    }

    // build z B-frags in registers (2 z-tiles x 4 ks x hi/lo) + norms
    bf16x8 Zh[2][4], Zl[2][4];
    float hzv[2];
#pragma unroll
    for (int zt = 0; zt < 2; zt++) {
        float ss = 0.f;
        const int hw = ((rb & 1) << 9) + w * 64 + zt * 32 + col;
        const float* zp = z + (size_t)b * CHW_ + hw;
#pragma unroll
        for (int ks = 0; ks < 4; ks++) {
            const int c0 = ks * 16 + kgrp * 8;
            float v[8];
#pragma unroll
            for (int j = 0; j < 8; j++) {
                v[j] = zp[(c0 + j) * HW_];
                ss = fmaf(v[j], v[j], ss);
            }
            FragU hi, lo;
            split8(v, hi, lo);
            Zh[zt][ks] = hi.v;
            Zl[zt][ks] = lo.v;
        }
        ss += __shfl_xor(ss, 32);      // other k-half of this z-row
        hzv[zt] = 0.5f * ss;
    }

    unsigned s1k[2] = {~0u, ~0u};
    unsigned s2k[2] = {~0u, ~0u};

    __syncthreads();                  // chunk 0 staged (barrier drains vmcnt)
    for (int c = 0; c < 4; c++) {
        if (c < 3) {                  // issue next-chunk stage early
            const char* src = efrag + (size_t)(e0t + (c + 1) * 4 + (w >> 1)) * 8192
                              + (w & 1) * 4096 + lane * 16;
            char* dst = buf[(c + 1) & 1] + (w >> 1) * 8192 + (w & 1) * 4096;
#pragma unroll
            for (int i = 0; i < 4; i++) gload_lds16(src + i * 1024, dst + i * 1024);
        }

#pragma unroll
        for (int jt = 0; jt < 4; jt++) {
            const char* tb = buf[c & 1] + jt * 8192 + lane * 16;
            bf16x8 Ah[4], Al[4];
#pragma unroll
            for (int ks = 0; ks < 4; ks++) {
                Ah[ks] = *(const bf16x8*)(tb + ks * 1024);
                Al[ks] = *(const bf16x8*)(tb + 4096 + ks * 1024);
            }
            const int tloc = c * 4 + jt;           // local tile32 0..15
            f32x4 he[4];
#pragma unroll
            for (int rq = 0; rq < 4; rq++)
                he[rq] = *(const f32x4*)&sh_he[tloc * 32 + 8 * rq + 4 * kgrp];

            f32x16 c0, c1;
#pragma unroll
            for (int rq = 0; rq < 4; rq++)
#pragma unroll
                for (int rr = 0; rr < 4; rr++) {
                    c0[rq * 4 + rr] = he[rq][rr] + hzv[0];
                    c1[rq * 4 + rr] = he[rq][rr] + hzv[1];
                }

            // term 1: eh . zh
#pragma unroll
            for (int ks = 0; ks < 4; ks++) {
                c0 = __builtin_amdgcn_mfma_f32_32x32x16_bf16(Ah[ks], Zh[0][ks], c0, 0, 0, 0);
                c1 = __builtin_amdgcn_mfma_f32_32x32x16_bf16(Ah[ks], Zh[1][ks], c1, 0, 0, 0);
            }
            // term 2: el . zh
#pragma unroll
            for (int ks = 0; ks < 4; ks++) {
                c0 = __builtin_amdgcn_mfma_f32_32x32x16_bf16(Al[ks], Zh[0][ks], c0, 0, 0, 0);
                c1 = __builtin_amdgcn_mfma_f32_32x32x16_bf16(Al[ks], Zh[1][ks], c1, 0, 0, 0);
            }
            // term 3: eh . zl
#pragma unroll
            for (int ks = 0; ks < 4; ks++) {
                c0 = __builtin_amdgcn_mfma_f32_32x32x16_bf16(Ah[ks], Zl[0][ks], c0, 0, 0, 0);
                c1 = __builtin_amdgcn_mfma_f32_32x32x16_bf16(Ah[ks], Zl[1][ks], c1, 0, 0, 0);
            }

            // keying: e_local = (reg&3) + 8*(reg>>2) + 4*kgrp
            const unsigned eb = (unsigned)(es * 512 + tloc * 32 + 4 * kgrp);
#pragma unroll
            for (int rq = 0; rq < 4; rq++)
#pragma unroll
                for (int rr = 0; rr < 4; rr++) {
                    const unsigned eo = eb + rr + 8 * rq;
                    top2_((__float_as_uint(c0[rq * 4 + rr]) & 0xFFFFF000u) | eo, s1k[0], s2k[0]);
                    top2_((__float_as_uint(c1[rq * 4 + rr]) & 0xFFFFF000u) | eo, s1k[1], s2k[1]);
                }
        }
        __syncthreads();              // next chunk landed; buf[c&1] free
    }

    // merge across the 2 k-octet lane halves (same z-col, disjoint e-sets)
#pragma unroll
    for (int r = 0; r < 2; r++) {
        unsigned o1 = (unsigned)__shfl_xor((int)s1k[r], 32);
        unsigned o2 = (unsigned)__shfl_xor((int)s2k[r], 32);
        s2k[r] = umin_(umin_(s2k[r], o2), umax_(s1k[r], o1));
        s1k[r] = umin_(s1k[r], o1);
    }

    if (lane < 32) {                  // plain stores; one owner per (row, es)
        const int base = es * 16384 + row0;
#pragma unroll
        for (int r = 0; r < 2; r++) {
            k1q[base + r * 32 + lane] = s1k[r];
            k2q[base + r * 32 + lane] = s2k[r];
        }
    }

    __threadfence();
    grid.sync();

    // ================= phase C: merge partials + outputs ==================
    if (tid < 256) {
        int t = blockIdx.x * 256 + tid;       // 65536 workers
        int n = t & 16383;
        int q = t >> 14;

        unsigned m = 0xFFFFFFFFu, s = 0xFFFFFFFFu;
#pragma unroll
        for (int i = 0; i < 8; i++) {
            unsigned a = k1q[i * 16384 + n];
            unsigned bb = k2q[i * 16384 + n];
            unsigned hi = umax_(m, a);
            m = umin_(m, a);
            s = umin_(umin_(s, bb), hi);
        }

        int idx = (int)(m & 0xFFFu);
        float sc1 = __uint_as_float(m & 0xFFFFF000u);
        float sc2 = __uint_as_float(s & 0xFFFFF000u);

        int bb2 = n >> 10, hw = n & 1023;
        const float* zp = z + (size_t)bb2 * CHW_ + hw;
        const int cq = q * 16;

        if (sc2 - sc1 < EPS_GAP) {             // near-tie: exact fp64 duel
            int i2 = (int)(s & 0xFFFu);
            const float* ea = emb + (size_t)idx * 64;
            const float* eb2 = emb + (size_t)i2 * 64;
            double da = 0.0, db = 0.0;
#pragma unroll 8
            for (int c = 0; c < 64; c++) {
                double zv = (double)zp[c * HW_];
                double xa = (double)ea[c] - zv;
                double xb = (double)eb2[c] - zv;
                da = fma(xa, xa, da);
                db = fma(xb, xb, db);
            }
            if (db < da || (db == da && i2 < idx)) idx = i2;
        }

        const float* er = emb + (size_t)idx * 64 + cq;
        float* zq = out + (size_t)bb2 * CHW_ + hw;
        float lsum = 0.f;
#pragma unroll
        for (int j = 0; j < 16; j++) {
            float e = er[j];
            float d = e - zp[(cq + j) * HW_];
            zq[(cq + j) * HW_] = e;
            lsum = fmaf(d, d, lsum);
        }
        if (q == 0) out[IDX_OFF + n] = (float)idx;

#pragma unroll
        for (int off = 32; off; off >>= 1) lsum += __shfl_down(lsum, off);
        if ((tid & 63) == 0) atomicAdd(&out[LOSS_OFF], lsum * LOSS_SCALE);
    }
}

extern "C" void kernel_launch(void* const* d_in, const int* in_sizes, int n_in,
                              void* d_out, int out_size, void* d_ws, size_t ws_size,
                              hipStream_t stream) {
    const float* z   = (const float*)d_in[0];
    const float* emb = (const float*)d_in[1];
    float* out = (float*)d_out;
    char* ws = (char*)d_ws;

    char* efrag   = ws;                               // 1 MB (128 x 8 KB)
    float* h_e    = (float*)(ws + 1048576);           // 16 KB
    unsigned* k1q = (unsigned*)(ws + 1065024);        // 512 KB (8 partials)
    unsigned* k2q = (unsigned*)(ws + 1589312);        // 512 KB

    void* args[] = {(void*)&z, (void*)&emb, (void*)&efrag, (void*)&h_e,
                    (void*)&k1q, (void*)&k2q, (void*)&out};
    hipLaunchCooperativeKernel((const void*)vq_all, dim3(256), dim3(512),
                               args, 0, stream);
}

// Round 25
// 63.485 us; speedup vs baseline: 3.0489x; 3.0489x over previous
//
#include <hip/hip_runtime.h>

typedef float f32x4 __attribute__((ext_vector_type(4)));
typedef float f32x16 __attribute__((ext_vector_type(16)));
typedef short bf16x8 __attribute__((ext_vector_type(8)));

#define HW_ 1024
#define NE_ 4096
#define CHW_ 65536          // 64*1024
#define ZQ_SIZE 1048576
#define LOSS_OFF ZQ_SIZE
#define IDX_OFF (ZQ_SIZE + 1)
#define LOSS_SCALE (1.25f / 1048576.f)
#define EPS_GAP 0.1f        // 0.5*d2 scale; covers 12-bit trunc (~0.016) + split err (~1e-5)

union FragU { unsigned u[4]; bf16x8 v; };

__device__ __forceinline__ unsigned umin_(unsigned a, unsigned b) { return a < b ? a : b; }
__device__ __forceinline__ unsigned umax_(unsigned a, unsigned b) { return a > b ? a : b; }

// running top-2 update: s2 = median(key, s1, s2) ; s1 = min(s1, key)
// NOT idempotent under duplicate streams (R19 lesson).
__device__ __forceinline__ void top2_(unsigned key, unsigned& s1, unsigned& s2) {
    unsigned t;
    asm("v_med3_u32 %0, %1, %2, %3" : "=v"(t) : "v"(key), "v"(s1), "v"(s2));
    s2 = t;
    s1 = umin_(s1, key);
}

// split 8 f32 -> hi/lo bf16 fragments (truncation split; lo captures the tail)
__device__ __forceinline__ void split8(const float* v, FragU& hi, FragU& lo) {
#pragma unroll
    for (int p = 0; p < 4; p++) {
        float a = v[2 * p], b = v[2 * p + 1];
        unsigned ua = __float_as_uint(a), ub = __float_as_uint(b);
        hi.u[p] = (ua >> 16) | (ub & 0xFFFF0000u);
        float la = a - __uint_as_float(ua & 0xFFFF0000u);
        float lb = b - __uint_as_float(ub & 0xFFFF0000u);
        lo.u[p] = (__float_as_uint(la) >> 16) | (__float_as_uint(lb) & 0xFFFF0000u);
    }
}

__device__ __forceinline__ void gload_lds16(const void* g, void* l) {
    __builtin_amdgcn_global_load_lds(
        (const __attribute__((address_space(1))) unsigned*)g,
        (__attribute__((address_space(3))) unsigned*)l, 16, 0, 0);
}

// ---- kernel 1: efrag32 (negated, split, 32x32x16 A-layout) + h_e ---------
// efrag32[tile(128)][part(hi,lo)][ks(4)][lane(64)] x 16B ; tile stride 8 KB.
// Lane l of (tile,ks) holds e-row = tile*32+(l&31), k = ks*16+(l>>5)*8+{0..7}.
__global__ __launch_bounds__(256) void vq_eprep(
        const float* __restrict__ emb, char* __restrict__ efrag,
        float* __restrict__ h_e, float* __restrict__ out) {
    const int bid = blockIdx.x, tid = threadIdx.x;
    if (bid < 128) {
        int u = bid * 256 + tid;              // 32768 threads
        int l = u & 63, ks = (u >> 6) & 3, t = u >> 8;   // t 0..127
        int erow = t * 32 + (l & 31);
        int k0 = ks * 16 + (l >> 5) * 8;
        const float* ep = emb + (size_t)erow * 64 + k0;
        float4 ea = *(const float4*)(ep);
        float4 eb = *(const float4*)(ep + 4);
        float v[8];
        v[0] = -ea.x; v[1] = -ea.y; v[2] = -ea.z; v[3] = -ea.w;
        v[4] = -eb.x; v[5] = -eb.y; v[6] = -eb.z; v[7] = -eb.w;
        FragU hi, lo;
        split8(v, hi, lo);
        char* base = efrag + (size_t)t * 8192 + ks * 1024 + l * 16;
        *(FragU*)(base)        = hi;
        *(FragU*)(base + 4096) = lo;
    } else {                               // h_e (16 blocks) + loss init
        int t = (bid - 128) * 256 + tid;   // 0..4095
        const float4* er = (const float4*)(emb + (size_t)t * 64);
        float s = 0.f;
#pragma unroll
        for (int k = 0; k < 16; k++) {
            float4 e4 = er[k];
            s = fmaf(e4.x, e4.x, s); s = fmaf(e4.y, e4.y, s);
            s = fmaf(e4.z, e4.z, s); s = fmaf(e4.w, e4.w, s);
        }
        h_e[t] = 0.5f * s;
        if (t == 0) out[LOSS_OFF] = 0.f;
    }
}

// ---- kernel 2: 32x32x16 MFMA scan (identical to R23) ---------------------
// Grid 256; es = bid>>5 (8 e-splits of 512 e = 16 tiles32), rb = bid&31
// (32 row-groups of 512): bid%8 == rb%8 -> same XCD -> z L2 reuse.
// Block = 8 waves; wave: 2 z-tiles of 32 rows (B-frags + hz in regs) x 512 e.
// e staged in 4-tile (32 KB) chunks, double-buffered via global_load_lds.
// Per 32-e tile: 8 A ds_reads + 4 he reads -> 24 MFMA (3-term split) ->
// 32 keys. C layout: col=lane&31, row=(reg&3)+8*(reg>>2)+4*(lane>>5).
// acc = 0.5|z|^2 + 0.5|e|^2 - e.z (err ~1e-5) = 0.5*d2 > 0.
// key = (f32 bits & ~0xFFF) | e_idx ; u32 min == lexicographic argmin.
__global__ __launch_bounds__(512) void vq_mfma(
        const float* __restrict__ z, const char* __restrict__ efrag,
        const float* __restrict__ h_e,
        unsigned* __restrict__ k1q, unsigned* __restrict__ k2q) {
    __shared__ char buf[2][32768];
    __shared__ __attribute__((aligned(16))) float sh_he[512];

    const int tid = threadIdx.x;
    const int lane = tid & 63;
    const int w = tid >> 6;
    const int col = lane & 31;
    const int kgrp = lane >> 5;       // k-octet group (0..1)
    const int es = blockIdx.x >> 5;   // e-split (512 e = 16 tiles32)
    const int rb = blockIdx.x & 31;   // row-group (512 rows); bid%8 == rb%8
    const int e0t = es * 16;          // first tile32 of split
    const int b = rb >> 1;            // batch image (block never crosses)
    const int row0 = rb * 512 + w * 64;   // wave's 64 rows (2 z-tiles)

    sh_he[tid] = h_e[es * 512 + tid];

    // stage chunk 0: wave w stages tile (w>>1), part (w&1)
    {
        const char* src = efrag + (size_t)(e0t + (w >> 1)) * 8192
                          + (w & 1) * 4096 + lane * 16;
        char* dst = buf[0] + (w >> 1) * 8192 + (w & 1) * 4096;
#pragma unroll
        for (int i = 0; i < 4; i++) gload_lds16(src + i * 1024, dst + i * 1024);
    }

    // build z B-frags in registers (2 z-tiles x 4 ks x hi/lo) + norms
    bf16x8 Zh[2][4], Zl[2][4];
    float hzv[2];
#pragma unroll
    for (int zt = 0; zt < 2; zt++) {
        float ss = 0.f;
        const int hw = ((rb & 1) << 9) + w * 64 + zt * 32 + col;
        const float* zp = z + (size_t)b * CHW_ + hw;
#pragma unroll
        for (int ks = 0; ks < 4; ks++) {
            const int c0 = ks * 16 + kgrp * 8;
            float v[8];
#pragma unroll
            for (int j = 0; j < 8; j++) {
                v[j] = zp[(c0 + j) * HW_];
                ss = fmaf(v[j], v[j], ss);
            }
            FragU hi, lo;
            split8(v, hi, lo);
            Zh[zt][ks] = hi.v;
            Zl[zt][ks] = lo.v;
        }
        ss += __shfl_xor(ss, 32);      // other k-half of this z-row
        hzv[zt] = 0.5f * ss;
    }

    unsigned s1k[2] = {~0u, ~0u};
    unsigned s2k[2] = {~0u, ~0u};

    __syncthreads();                  // chunk 0 staged (barrier drains vmcnt)
    for (int c = 0; c < 4; c++) {
        if (c < 3) {                  // issue next-chunk stage early
            const char* src = efrag + (size_t)(e0t + (c + 1) * 4 + (w >> 1)) * 8192
                              + (w & 1) * 4096 + lane * 16;
            char* dst = buf[(c + 1) & 1] + (w >> 1) * 8192 + (w & 1) * 4096;
#pragma unroll
            for (int i = 0; i < 4; i++) gload_lds16(src + i * 1024, dst + i * 1024);
        }

#pragma unroll
        for (int jt = 0; jt < 4; jt++) {
            const char* tb = buf[c & 1] + jt * 8192 + lane * 16;
            bf16x8 Ah[4], Al[4];
#pragma unroll
            for (int ks = 0; ks < 4; ks++) {
                Ah[ks] = *(const bf16x8*)(tb + ks * 1024);
                Al[ks] = *(const bf16x8*)(tb + 4096 + ks * 1024);
            }
            const int tloc = c * 4 + jt;           // local tile32 0..15
            f32x4 he[4];
#pragma unroll
            for (int rq = 0; rq < 4; rq++)
                he[rq] = *(const f32x4*)&sh_he[tloc * 32 + 8 * rq + 4 * kgrp];

            f32x16 c0, c1;
#pragma unroll
            for (int rq = 0; rq < 4; rq++)
#pragma unroll
                for (int rr = 0; rr < 4; rr++) {
                    c0[rq * 4 + rr] = he[rq][rr] + hzv[0];
                    c1[rq * 4 + rr] = he[rq][rr] + hzv[1];
                }

            // term 1: eh . zh
#pragma unroll
            for (int ks = 0; ks < 4; ks++) {
                c0 = __builtin_amdgcn_mfma_f32_32x32x16_bf16(Ah[ks], Zh[0][ks], c0, 0, 0, 0);
                c1 = __builtin_amdgcn_mfma_f32_32x32x16_bf16(Ah[ks], Zh[1][ks], c1, 0, 0, 0);
            }
            // term 2: el . zh
#pragma unroll
            for (int ks = 0; ks < 4; ks++) {
                c0 = __builtin_amdgcn_mfma_f32_32x32x16_bf16(Al[ks], Zh[0][ks], c0, 0, 0, 0);
                c1 = __builtin_amdgcn_mfma_f32_32x32x16_bf16(Al[ks], Zh[1][ks], c1, 0, 0, 0);
            }
            // term 3: eh . zl
#pragma unroll
            for (int ks = 0; ks < 4; ks++) {
                c0 = __builtin_amdgcn_mfma_f32_32x32x16_bf16(Ah[ks], Zl[0][ks], c0, 0, 0, 0);
                c1 = __builtin_amdgcn_mfma_f32_32x32x16_bf16(Ah[ks], Zl[1][ks], c1, 0, 0, 0);
            }

            // keying: e_local = (reg&3) + 8*(reg>>2) + 4*kgrp
            const unsigned eb = (unsigned)(es * 512 + tloc * 32 + 4 * kgrp);
#pragma unroll
            for (int rq = 0; rq < 4; rq++)
#pragma unroll
                for (int rr = 0; rr < 4; rr++) {
                    const unsigned eo = eb + rr + 8 * rq;
                    top2_((__float_as_uint(c0[rq * 4 + rr]) & 0xFFFFF000u) | eo, s1k[0], s2k[0]);
                    top2_((__float_as_uint(c1[rq * 4 + rr]) & 0xFFFFF000u) | eo, s1k[1], s2k[1]);
                }
        }
        __syncthreads();              // next chunk landed; buf[c&1] free
    }

    // merge across the 2 k-octet lane halves (same z-col, disjoint e-sets)
#pragma unroll
    for (int r = 0; r < 2; r++) {
        unsigned o1 = (unsigned)__shfl_xor((int)s1k[r], 32);
        unsigned o2 = (unsigned)__shfl_xor((int)s2k[r], 32);
        s2k[r] = umin_(umin_(s2k[r], o2), umax_(s1k[r], o1));
        s1k[r] = umin_(s1k[r], o1);
    }

    if (lane < 32) {                  // plain stores; one owner per (row, es)
        const int base = es * 16384 + row0;
#pragma unroll
        for (int r = 0; r < 2; r++) {
            k1q[base + r * 32 + lane] = s1k[r];
            k2q[base + r * 32 + lane] = s2k[r];
        }
    }
}

// ---- kernel 3: merge 8 partials; outputs; fp64 duel for near-ties --------
// Plane-major, 8 threads/row: thread t -> row n = t & 16383, eighth q = t>>14.
__global__ __launch_bounds__(256) void vq_final(
        const float* __restrict__ z, const float* __restrict__ emb,
        const unsigned* __restrict__ k1q, const unsigned* __restrict__ k2q,
        float* __restrict__ out) {
    int t = blockIdx.x * 256 + threadIdx.x;   // 512 blocks x 256 = 131072
    int n = t & 16383;
    int q = t >> 14;                          // 0..7

    unsigned m = 0xFFFFFFFFu, s = 0xFFFFFFFFu;
#pragma unroll
    for (int i = 0; i < 8; i++) {
        unsigned a = k1q[i * 16384 + n];
        unsigned b = k2q[i * 16384 + n];
        unsigned hi = umax_(m, a);
        m = umin_(m, a);
        s = umin_(umin_(s, b), hi);
    }

    int idx = (int)(m & 0xFFFu);
    float s1 = __uint_as_float(m & 0xFFFFF000u);
    float s2 = __uint_as_float(s & 0xFFFFF000u);

    int b = n >> 10, hw = n & 1023;
    const float* zp = z + (size_t)b * CHW_ + hw;
    const int cq = q * 8;

    if (s2 - s1 < EPS_GAP) {                   // near-tie: exact fp64 duel
        int i2 = (int)(s & 0xFFFu);
        const float* ea = emb + (size_t)idx * 64;
        const float* eb = emb + (size_t)i2 * 64;
        double da = 0.0, db = 0.0;
#pragma unroll 8
        for (int c = 0; c < 64; c++) {
            double zv = (double)zp[c * HW_];
            double xa = (double)ea[c] - zv;
            double xb = (double)eb[c] - zv;
            da = fma(xa, xa, da);
            db = fma(xb, xb, db);
        }
        if (db < da || (db == da && i2 < idx)) idx = i2;
    }

    const float* er = emb + (size_t)idx * 64 + cq;
    float* zq = out + (size_t)b * CHW_ + hw;
    float lsum = 0.f;
#pragma unroll
    for (int j = 0; j < 8; j++) {
        float e = er[j];
        float d = e - zp[(cq + j) * HW_];
        zq[(cq + j) * HW_] = e;
        lsum = fmaf(d, d, lsum);
    }
    if (q == 0) out[IDX_OFF + n] = (float)idx;

#pragma unroll
    for (int off = 32; off; off >>= 1) lsum += __shfl_down(lsum, off);
    if ((threadIdx.x & 63) == 0) atomicAdd(&out[LOSS_OFF], lsum * LOSS_SCALE);
}

extern "C" void kernel_launch(void* const* d_in, const int* in_sizes, int n_in,
                              void* d_out, int out_size, void* d_ws, size_t ws_size,
                              hipStream_t stream) {
    const float* z   = (const float*)d_in[0];
    const float* emb = (const float*)d_in[1];
    float* out = (float*)d_out;
    char* ws = (char*)d_ws;

    char* efrag   = ws;                               // 1 MB (128 x 8 KB)
    float* h_e    = (float*)(ws + 1048576);           // 16 KB
    unsigned* k1q = (unsigned*)(ws + 1065024);        // 512 KB (8 partials)
    unsigned* k2q = (unsigned*)(ws + 1589312);        // 512 KB

    vq_eprep<<<144, 256, 0, stream>>>(emb, efrag, h_e, out);
    vq_mfma <<<256, 512, 0, stream>>>(z, efrag, h_e, k1q, k2q);
    vq_final<<<512, 256, 0, stream>>>(z, emb, k1q, k2q, out);
}

// Round 26
// 50.778 us; speedup vs baseline: 3.8119x; 1.2503x over previous
//
#include <hip/hip_runtime.h>

typedef float f32x4 __attribute__((ext_vector_type(4)));
typedef float f32x16 __attribute__((ext_vector_type(16)));
typedef short bf16x8 __attribute__((ext_vector_type(8)));

#define HW_ 1024
#define NE_ 4096
#define CHW_ 65536          // 64*1024
#define ZQ_SIZE 1048576
#define LOSS_OFF ZQ_SIZE
#define IDX_OFF (ZQ_SIZE + 1)
#define LOSS_SCALE (1.25f / 1048576.f)
#define EPS_GAP 0.1f        // 0.5*d2 scale; covers 12-bit trunc (~0.016) + split err (~1e-5)

union FragU { unsigned u[4]; bf16x8 v; };

__device__ __forceinline__ unsigned umin_(unsigned a, unsigned b) { return a < b ? a : b; }
__device__ __forceinline__ unsigned umax_(unsigned a, unsigned b) { return a > b ? a : b; }

// running top-2 update: s2 = median(key, s1, s2) ; s1 = min(s1, key)
// NOT idempotent under duplicate streams (R19 lesson).
__device__ __forceinline__ void top2_(unsigned key, unsigned& s1, unsigned& s2) {
    unsigned t;
    asm("v_med3_u32 %0, %1, %2, %3" : "=v"(t) : "v"(key), "v"(s1), "v"(s2));
    s2 = t;
    s1 = umin_(s1, key);
}

// split 8 f32 -> hi/lo bf16 fragments (truncation split; lo captures the tail)
__device__ __forceinline__ void split8(const float* v, FragU& hi, FragU& lo) {
#pragma unroll
    for (int p = 0; p < 4; p++) {
        float a = v[2 * p], b = v[2 * p + 1];
        unsigned ua = __float_as_uint(a), ub = __float_as_uint(b);
        hi.u[p] = (ua >> 16) | (ub & 0xFFFF0000u);
        float la = a - __uint_as_float(ua & 0xFFFF0000u);
        float lb = b - __uint_as_float(ub & 0xFFFF0000u);
        lo.u[p] = (__float_as_uint(la) >> 16) | (__float_as_uint(lb) & 0xFFFF0000u);
    }
}

__device__ __forceinline__ void gload_lds16(const void* g, void* l) {
    __builtin_amdgcn_global_load_lds(
        (const __attribute__((address_space(1))) unsigned*)g,
        (__attribute__((address_space(3))) unsigned*)l, 16, 0, 0);
}

// ---- kernel 1: efrag32 (negated, split, 32x32x16 A-layout) + h_e ---------
// efrag32[tile(128)][part(hi,lo)][ks(4)][lane(64)] x 16B ; tile stride 8 KB.
// Lane l of (tile,ks) holds e-row = tile*32+(l&31), k = ks*16+(l>>5)*8+{0..7}.
__global__ __launch_bounds__(256) void vq_eprep(
        const float* __restrict__ emb, char* __restrict__ efrag,
        float* __restrict__ h_e, float* __restrict__ out) {
    const int bid = blockIdx.x, tid = threadIdx.x;
    if (bid < 128) {
        int u = bid * 256 + tid;              // 32768 threads
        int l = u & 63, ks = (u >> 6) & 3, t = u >> 8;   // t 0..127
        int erow = t * 32 + (l & 31);
        int k0 = ks * 16 + (l >> 5) * 8;
        const float* ep = emb + (size_t)erow * 64 + k0;
        float4 ea = *(const float4*)(ep);
        float4 eb = *(const float4*)(ep + 4);
        float v[8];
        v[0] = -ea.x; v[1] = -ea.y; v[2] = -ea.z; v[3] = -ea.w;
        v[4] = -eb.x; v[5] = -eb.y; v[6] = -eb.z; v[7] = -eb.w;
        FragU hi, lo;
        split8(v, hi, lo);
        char* base = efrag + (size_t)t * 8192 + ks * 1024 + l * 16;
        *(FragU*)(base)        = hi;
        *(FragU*)(base + 4096) = lo;
    } else {                               // h_e (16 blocks) + loss init
        int t = (bid - 128) * 256 + tid;   // 0..4095
        const float4* er = (const float4*)(emb + (size_t)t * 64);
        float s = 0.f;
#pragma unroll
        for (int k = 0; k < 16; k++) {
            float4 e4 = er[k];
            s = fmaf(e4.x, e4.x, s); s = fmaf(e4.y, e4.y, s);
            s = fmaf(e4.z, e4.z, s); s = fmaf(e4.w, e4.w, s);
        }
        h_e[t] = 0.5f * s;
        if (t == 0) out[LOSS_OFF] = 0.f;
    }
}

// ---- kernel 2: 32x32x16 MFMA scan ----------------------------------------
// Grid 256; es = bid>>5 (8 e-splits of 512 e = 16 tiles32), rb = bid&31
// (32 row-groups of 512): bid%8 == rb%8 -> same XCD -> z L2 reuse.
// Block = 8 waves; wave: 2 z-tiles of 32 rows (B-frags + hz in regs) x 512 e.
// e staged in 4-tile (32 KB) chunks, double-buffered via global_load_lds.
// Per 32-e tile: 8 A ds_reads + 4 he reads -> 24 MFMA (3-term split) ->
// 32 keys. C layout: col=lane&31, row=(reg&3)+8*(reg>>2)+4*(lane>>5).
// acc = 0.5|z|^2 + 0.5|e|^2 - e.z (err ~1e-5) = 0.5*d2 > 0.
// key = (f32 bits & ~0xFFF) | e_idx ; u32 min == lexicographic argmin.
__global__ __launch_bounds__(512) void vq_mfma(
        const float* __restrict__ z, const char* __restrict__ efrag,
        const float* __restrict__ h_e,
        unsigned* __restrict__ k1q, unsigned* __restrict__ k2q) {
    __shared__ char buf[2][32768];
    __shared__ __attribute__((aligned(16))) float sh_he[512];

    const int tid = threadIdx.x;
    const int lane = tid & 63;
    const int w = tid >> 6;
    const int col = lane & 31;
    const int kgrp = lane >> 5;       // k-octet group (0..1)
    const int es = blockIdx.x >> 5;   // e-split (512 e = 16 tiles32)
    const int rb = blockIdx.x & 31;   // row-group (512 rows); bid%8 == rb%8
    const int e0t = es * 16;          // first tile32 of split
    const int b = rb >> 1;            // batch image (block never crosses)
    const int row0 = rb * 512 + w * 64;   // wave's 64 rows (2 z-tiles)

    sh_he[tid] = h_e[es * 512 + tid];

    // stage chunk 0: wave w stages tile (w>>1), part (w&1)
    {
        const char* src = efrag + (size_t)(e0t + (w >> 1)) * 8192
                          + (w & 1) * 4096 + lane * 16;
        char* dst = buf[0] + (w >> 1) * 8192 + (w & 1) * 4096;
#pragma unroll
        for (int i = 0; i < 4; i++) gload_lds16(src + i * 1024, dst + i * 1024);
    }

    // build z B-frags in registers (2 z-tiles x 4 ks x hi/lo) + norms
    bf16x8 Zh[2][4], Zl[2][4];
    float hzv[2];
#pragma unroll
    for (int zt = 0; zt < 2; zt++) {
        float ss = 0.f;
        const int hw = ((rb & 1) << 9) + w * 64 + zt * 32 + col;
        const float* zp = z + (size_t)b * CHW_ + hw;
#pragma unroll
        for (int ks = 0; ks < 4; ks++) {
            const int c0 = ks * 16 + kgrp * 8;
            float v[8];
#pragma unroll
            for (int j = 0; j < 8; j++) {
                v[j] = zp[(c0 + j) * HW_];
                ss = fmaf(v[j], v[j], ss);
            }
            FragU hi, lo;
            split8(v, hi, lo);
            Zh[zt][ks] = hi.v;
            Zl[zt][ks] = lo.v;
        }
        ss += __shfl_xor(ss, 32);      // other k-half of this z-row
        hzv[zt] = 0.5f * ss;
    }

    unsigned s1k[2] = {~0u, ~0u};
    unsigned s2k[2] = {~0u, ~0u};

    __syncthreads();                  // chunk 0 staged (barrier drains vmcnt)
    for (int c = 0; c < 4; c++) {
        if (c < 3) {                  // issue next-chunk stage early
            const char* src = efrag + (size_t)(e0t + (c + 1) * 4 + (w >> 1)) * 8192
                              + (w & 1) * 4096 + lane * 16;
            char* dst = buf[(c + 1) & 1] + (w >> 1) * 8192 + (w & 1) * 4096;
#pragma unroll
            for (int i = 0; i < 4; i++) gload_lds16(src + i * 1024, dst + i * 1024);
        }

#pragma unroll
        for (int jt = 0; jt < 4; jt++) {
            const char* tb = buf[c & 1] + jt * 8192 + lane * 16;
            bf16x8 Ah[4], Al[4];
#pragma unroll
            for (int ks = 0; ks < 4; ks++) {
                Ah[ks] = *(const bf16x8*)(tb + ks * 1024);
                Al[ks] = *(const bf16x8*)(tb + 4096 + ks * 1024);
            }
            const int tloc = c * 4 + jt;           // local tile32 0..15
            f32x4 he[4];
#pragma unroll
            for (int rq = 0; rq < 4; rq++)
                he[rq] = *(const f32x4*)&sh_he[tloc * 32 + 8 * rq + 4 * kgrp];

            f32x16 c0, c1;
#pragma unroll
            for (int rq = 0; rq < 4; rq++)
#pragma unroll
                for (int rr = 0; rr < 4; rr++) {
                    c0[rq * 4 + rr] = he[rq][rr] + hzv[0];
                    c1[rq * 4 + rr] = he[rq][rr] + hzv[1];
                }

            // term 1: eh . zh
#pragma unroll
            for (int ks = 0; ks < 4; ks++) {
                c0 = __builtin_amdgcn_mfma_f32_32x32x16_bf16(Ah[ks], Zh[0][ks], c0, 0, 0, 0);
                c1 = __builtin_amdgcn_mfma_f32_32x32x16_bf16(Ah[ks], Zh[1][ks], c1, 0, 0, 0);
            }
            // term 2: el . zh
#pragma unroll
            for (int ks = 0; ks < 4; ks++) {
                c0 = __builtin_amdgcn_mfma_f32_32x32x16_bf16(Al[ks], Zh[0][ks], c0, 0, 0, 0);
                c1 = __builtin_amdgcn_mfma_f32_32x32x16_bf16(Al[ks], Zh[1][ks], c1, 0, 0, 0);
            }
            // term 3: eh . zl
#pragma unroll
            for (int ks = 0; ks < 4; ks++) {
                c0 = __builtin_amdgcn_mfma_f32_32x32x16_bf16(Ah[ks], Zl[0][ks], c0, 0, 0, 0);
                c1 = __builtin_amdgcn_mfma_f32_32x32x16_bf16(Ah[ks], Zl[1][ks], c1, 0, 0, 0);
            }

            // keying: e_local = (reg&3) + 8*(reg>>2) + 4*kgrp
            const unsigned eb = (unsigned)(es * 512 + tloc * 32 + 4 * kgrp);
#pragma unroll
            for (int rq = 0; rq < 4; rq++)
#pragma unroll
                for (int rr = 0; rr < 4; rr++) {
                    const unsigned eo = eb + rr + 8 * rq;
                    top2_((__float_as_uint(c0[rq * 4 + rr]) & 0xFFFFF000u) | eo, s1k[0], s2k[0]);
                    top2_((__float_as_uint(c1[rq * 4 + rr]) & 0xFFFFF000u) | eo, s1k[1], s2k[1]);
                }
        }
        __syncthreads();              // next chunk landed; buf[c&1] free
    }

    // merge across the 2 k-octet lane halves (same z-col, disjoint e-sets)
#pragma unroll
    for (int r = 0; r < 2; r++) {
        unsigned o1 = (unsigned)__shfl_xor((int)s1k[r], 32);
        unsigned o2 = (unsigned)__shfl_xor((int)s2k[r], 32);
        s2k[r] = umin_(umin_(s2k[r], o2), umax_(s1k[r], o1));
        s1k[r] = umin_(s1k[r], o1);
    }

    if (lane < 32) {                  // plain stores; one owner per (row, es)
        const int base = es * 16384 + row0;
#pragma unroll
        for (int r = 0; r < 2; r++) {
            k1q[base + r * 32 + lane] = s1k[r];
            k2q[base + r * 32 + lane] = s2k[r];
        }
    }
}

// ---- kernel 3: merge 8 partials; outputs; fp64 duel for near-ties --------
// Plane-major: thread t -> row n = t & 16383, channel quarter q = t >> 14.
__global__ __launch_bounds__(256) void vq_final(
        const float* __restrict__ z, const float* __restrict__ emb,
        const unsigned* __restrict__ k1q, const unsigned* __restrict__ k2q,
        float* __restrict__ out) {
    int t = blockIdx.x * 256 + threadIdx.x;   // 256 blocks x 256 = 65536
    int n = t & 16383;
    int q = t >> 14;

    unsigned m = 0xFFFFFFFFu, s = 0xFFFFFFFFu;
#pragma unroll
    for (int i = 0; i < 8; i++) {
        unsigned a = k1q[i * 16384 + n];
        unsigned b = k2q[i * 16384 + n];
        unsigned hi = umax_(m, a);
        m = umin_(m, a);
        s = umin_(umin_(s, b), hi);
    }

    int idx = (int)(m & 0xFFFu);
    float s1 = __uint_as_float(m & 0xFFFFF000u);
    float s2 = __uint_as_float(s & 0xFFFFF000u);

    int b = n >> 10, hw = n & 1023;
    const float* zp = z + (size_t)b * CHW_ + hw;
    const int cq = q * 16;

    if (s2 - s1 < EPS_GAP) {                   // near-tie: exact fp64 duel
        int i2 = (int)(s & 0xFFFu);
        const float* ea = emb + (size_t)idx * 64;
        const float* eb = emb + (size_t)i2 * 64;
        double da = 0.0, db = 0.0;
#pragma unroll 8
        for (int c = 0; c < 64; c++) {
            double zv = (double)zp[c * HW_];
            double xa = (double)ea[c] - zv;
            double xb = (double)eb[c] - zv;
            da = fma(xa, xa, da);
            db = fma(xb, xb, db);
        }
        if (db < da || (db == da && i2 < idx)) idx = i2;
    }

    const float* er = emb + (size_t)idx * 64 + cq;
    float* zq = out + (size_t)b * CHW_ + hw;
    float lsum = 0.f;
#pragma unroll
    for (int j = 0; j < 16; j++) {
        float e = er[j];
        float d = e - zp[(cq + j) * HW_];
        zq[(cq + j) * HW_] = e;
        lsum = fmaf(d, d, lsum);
    }
    if (q == 0) out[IDX_OFF + n] = (float)idx;

#pragma unroll
    for (int off = 32; off; off >>= 1) lsum += __shfl_down(lsum, off);
    if ((threadIdx.x & 63) == 0) atomicAdd(&out[LOSS_OFF], lsum * LOSS_SCALE);
}

extern "C" void kernel_launch(void* const* d_in, const int* in_sizes, int n_in,
                              void* d_out, int out_size, void* d_ws, size_t ws_size,
                              hipStream_t stream) {
    const float* z   = (const float*)d_in[0];
    const float* emb = (const float*)d_in[1];
    float* out = (float*)d_out;
    char* ws = (char*)d_ws;

    char* efrag   = ws;                               // 1 MB (128 x 8 KB)
    float* h_e    = (float*)(ws + 1048576);           // 16 KB
    unsigned* k1q = (unsigned*)(ws + 1065024);        // 512 KB (8 partials)
    unsigned* k2q = (unsigned*)(ws + 1589312);        // 512 KB

    vq_eprep<<<144, 256, 0, stream>>>(emb, efrag, h_e, out);
    vq_mfma <<<256, 512, 0, stream>>>(z, efrag, h_e, k1q, k2q);
    vq_final<<<256, 256, 0, stream>>>(z, emb, k1q, k2q, out);
}